// Round 12
// baseline (30.770 us; speedup 1.0000x reference)
//
#include <hip/hip_runtime.h>
#include <math.h>

#define THR_BASE 9.42477e-5f  // sin(3e-4 * pi/10): proven margin (rounds 2-11)
#define KFOLD 256.0f          // count-fold constant: hist[fl] += mag + KFOLD
#define KFOLD_INV 0.00390625f // 1/256

// Predicated (border) halo row load
#define LOADROW_P(DST, RR)                                                \
    {                                                                     \
        int rr = (RR);                                                    \
        bool rok = (rr >= 0) && (rr < 512);                               \
        const float* rp = img + (size_t)(rok ? rr : row0) * 512;          \
        const float4* rp4 = (const float4*)(rp + col0);                   \
        float4 v0 = rp4[0], v1 = rp4[1];                                  \
        float lf = rp[(cw > 0) ? (col0 - 1) : col0];                      \
        float rt = rp[(cw < 63) ? (col0 + 8) : col0];                     \
        float m = rok ? 1.0f : 0.0f;                                      \
        DST[0] = (cw > 0 && rok) ? lf : 0.0f;                             \
        DST[1] = v0.x * m; DST[2] = v0.y * m;                             \
        DST[3] = v0.z * m; DST[4] = v0.w * m;                             \
        DST[5] = v1.x * m; DST[6] = v1.y * m;                             \
        DST[7] = v1.z * m; DST[8] = v1.w * m;                             \
        DST[9] = (cw < 63 && rok) ? rt : 0.0f;                            \
    }

// Unpredicated (interior-wave) halo row load
#define LOADROW_F(DST, RR)                                                \
    {                                                                     \
        const float* rp = img + (size_t)(RR) * 512;                       \
        const float4* rp4 = (const float4*)(rp + col0);                   \
        float4 v0 = rp4[0], v1 = rp4[1];                                  \
        DST[0] = rp[col0 - 1];                                            \
        DST[1] = v0.x; DST[2] = v0.y; DST[3] = v0.z; DST[4] = v0.w;       \
        DST[5] = v1.x; DST[6] = v1.y; DST[7] = v1.z; DST[8] = v1.w;       \
        DST[9] = rp[col0 + 8];                                            \
    }

// x: (16,1,512,512) f32 ; out: (16,10,64,64) f32
// thread t -> (n, ch, cw, r2): r2 = t & 3 selects a 2-row pair of the 8x8
// cell. 4 threads/cell, 16 px/thread. Per-LANE private LDS histogram:
// ds_add_f32 scatter (1 op/px) replaces the 30-instr select-chain.
__global__ void __launch_bounds__(256) hog_kernel(const float* __restrict__ x,
                                                  float* __restrict__ out) {
    __shared__ float hist[256 * 11];   // 11-word stride: bank spread, private
    float* myh = &hist[threadIdx.x * 11];
#pragma unroll
    for (int b = 0; b < 10; ++b) myh[b] = 0.0f;
    // No __syncthreads needed: each lane touches only its own region, and
    // same-wave DS ops complete in order.

    int t    = blockIdx.x * 256 + threadIdx.x;
    int r2   = t & 3;            // row-pair within cell
    int cell = t >> 2;           // 0 .. 65535
    int cw   = cell & 63;
    int ch   = (cell >> 6) & 63;
    int n    = cell >> 12;

    const float* img = x + (size_t)n * (512 * 512);
    int row0 = ch * 8 + r2 * 2;  // first of this thread's 2 pixel rows
    int col0 = cw * 8;

    // ---- Phase 1: 4 halo rows -> dd (col sums) / uu (row diffs) ----
    float dd0[10], dd1[10], uu0[10], uu1[10];
    {
        float t0[10], t1[10], t2[10], t3[10];
        bool border = (cw == 0) | (cw == 63)
                    | ((ch == 0) & (r2 == 0)) | ((ch == 63) & (r2 == 3));
        if (__any((int)border)) {
            LOADROW_P(t0, row0 - 1)
            LOADROW_P(t1, row0)
            LOADROW_P(t2, row0 + 1)
            LOADROW_P(t3, row0 + 2)
        } else {
            LOADROW_F(t0, row0 - 1)
            LOADROW_F(t1, row0)
            LOADROW_F(t2, row0 + 1)
            LOADROW_F(t3, row0 + 2)
        }
#pragma unroll
        for (int c = 0; c < 10; ++c) {
            dd0[c] = fmaf(2.0f, t1[c], t0[c] + t2[c]);  // pixel row row0
            dd1[c] = fmaf(2.0f, t2[c], t1[c] + t3[c]);  // pixel row row0+1
            uu0[c] = t0[c] - t2[c];
            uu1[c] = t1[c] - t3[c];
        }
    }   // t0..t3 dead here

    // ---- Phase 2: all 16 gx / gy ----
    float gx[16], gy[16];
#pragma unroll
    for (int c = 0; c < 8; ++c) {
        gx[c]     = dd0[c] - dd0[c + 2];
        gx[8 + c] = dd1[c] - dd1[c + 2];
        gy[c]     = fmaf(2.0f, uu0[c + 1], uu0[c] + uu0[c + 2]);
        gy[8 + c] = fmaf(2.0f, uu1[c + 1], uu1[c] + uu1[c + 2]);
    }

    // ---- Phase 3: hot loop over 16 pixels ----
    unsigned bmask = 0u;            // boundary-pixel flags (rare), 16 bits

#pragma unroll
    for (int p = 0; p < 16; ++p) {
        float gxc = gx[p], gyc = gy[p];
        float mag = __builtin_amdgcn_sqrtf(fmaf(gxc, gxc, gyc * gyc));
        float a = fabsf(gxc), b = fabsf(gyc);

        // Sector tests: m_k = a*cos(k*pi/10) - b*sin(k*pi/10), k=1..4
        float m1 = fmaf(a, 0.95105651629515353f, -(b * 0.30901699437494740f));
        float m2 = fmaf(a, 0.80901699437494745f, -(b * 0.58778525229247314f));
        float m3 = fmaf(a, 0.58778525229247314f, -(b * 0.80901699437494745f));
        float m4 = fmaf(a, 0.30901699437494740f, -(b * 0.95105651629515353f));
        int neg = (int)(__float_as_uint(m1) >> 31) + (int)(__float_as_uint(m2) >> 31)
                + (int)(__float_as_uint(m3) >> 31) + (int)(__float_as_uint(m4) >> 31);
        bool qq = (((__float_as_uint(gxc) ^ __float_as_uint(gyc)) >> 31) != 0u);
        int fl = qq ? (5 + neg) : (4 - neg);

        float dmin = fminf(fminf(fminf(fabsf(m1), fabsf(m2)),
                                 fminf(fabsf(m3), fabsf(m4))),
                           fminf(a, b));
        bmask = (dmin < THR_BASE * fmaxf(mag, 1.0f)) ? (bmask | (1u << p)) : bmask;

        // Private-lane scatter accumulate: one ds_add_f32, no contention.
        atomicAdd(&myh[fl], mag + KFOLD);
    }

    // ---- Rare fixup: undo fast contribution, apply exact f64 sector ----
    while (__any((int)(bmask != 0u))) {
        if (bmask) {
            int p = (int)__builtin_ctz(bmask);
            bmask &= bmask - 1u;
            int prow = row0 + (p >> 3);
            int pc   = col0 + (p & 7);
            int rm = prow - 1, rq = prow + 1;
            int cm = pc - 1, cp = pc + 1;
            bool rmok = rm >= 0, rqok = rq < 512;
            bool cmok = cm >= 0, cpok = cp < 512;
            float w00 = (rmok && cmok) ? img[(size_t)rm * 512 + cm] : 0.0f;
            float w01 = rmok ? img[(size_t)rm * 512 + pc] : 0.0f;
            float w02 = (rmok && cpok) ? img[(size_t)rm * 512 + cp] : 0.0f;
            float w10 = cmok ? img[(size_t)prow * 512 + cm] : 0.0f;
            float w12 = cpok ? img[(size_t)prow * 512 + cp] : 0.0f;
            float w20 = (rqok && cmok) ? img[(size_t)rq * 512 + cm] : 0.0f;
            float w21 = rqok ? img[(size_t)rq * 512 + pc] : 0.0f;
            float w22 = (rqok && cpok) ? img[(size_t)rq * 512 + cp] : 0.0f;

            // Bit-exact replication of the fast path (same op forms/values)
            float gxf = fmaf(2.0f, w10, w00 + w20) - fmaf(2.0f, w12, w02 + w22);
            float gyf = fmaf(2.0f, w01 - w21, (w00 - w20) + (w02 - w22));
            float magf = __builtin_amdgcn_sqrtf(fmaf(gxf, gxf, gyf * gyf));
            int negf = (int)(__float_as_uint(fmaf(fabsf(gxf), 0.95105651629515353f, -(fabsf(gyf) * 0.30901699437494740f))) >> 31)
                     + (int)(__float_as_uint(fmaf(fabsf(gxf), 0.80901699437494745f, -(fabsf(gyf) * 0.58778525229247314f))) >> 31)
                     + (int)(__float_as_uint(fmaf(fabsf(gxf), 0.58778525229247314f, -(fabsf(gyf) * 0.80901699437494745f))) >> 31)
                     + (int)(__float_as_uint(fmaf(fabsf(gxf), 0.30901699437494740f, -(fabsf(gyf) * 0.95105651629515353f))) >> 31);
            bool qqf = (((__float_as_uint(gxf) ^ __float_as_uint(gyf)) >> 31) != 0u);
            int flf = qqf ? (5 + negf) : (4 - negf);

            // Undo fast contribution (magnitude + folded count)
            atomicAdd(&myh[flf], -(magf + KFOLD));

            // Exact f64 sector classification (no atan2).
            double gxd = (((((double)w00 - (double)w02) + 2.0 * (double)w10)
                           - 2.0 * (double)w12) + (double)w20) - (double)w22;
            double gyd = (((((double)w00 + 2.0 * (double)w01) + (double)w02)
                           - (double)w20) - 2.0 * (double)w21) - (double)w22;
            int fls;
            float mvals;
            if (gxd == 0.0) { fls = 0; mvals = 1.0f; }        // p = 0 / +-10
            else if (gyd == 0.0) { fls = 5; mvals = 1.0f; }   // p = +-5
            else {
                double ad = fabs(gxd), bd = fabs(gyd);
                double M1 = fma(ad, 0.95105651629515353118, -(bd * 0.30901699437494742410));
                double M2 = fma(ad, 0.80901699437494742410, -(bd * 0.58778525229247312917));
                double M3 = fma(ad, 0.58778525229247312917, -(bd * 0.80901699437494742410));
                double M4 = fma(ad, 0.30901699437494742410, -(bd * 0.95105651629515353118));
                int negd = (int)(M1 < 0.0) + (int)(M2 < 0.0)
                         + (int)(M3 < 0.0) + (int)(M4 < 0.0);
                bool qd = (gxd < 0.0) != (gyd < 0.0);
                fls = qd ? (5 + negd) : (4 - negd);
                mvals = magf;
            }
            atomicAdd(&myh[fls], mvals + KFOLD);
        }
    }

    // ---- Tail: read back private bins, unfold counts, combine, reduce ----
    // Same-wave DS ordering guarantees the adds above are visible.
    float sm[10], nb[10];
#pragma unroll
    for (int b = 0; b < 10; ++b) {
        float c = myh[b];
        float q = rintf(c * KFOLD_INV);
        sm[b] = fmaf(q, -KFOLD, c);
        nb[b] = q;
    }
    float* op = out + (((size_t)n * 10) * 64 + ch) * 64 + cw;
#pragma unroll
    for (int b = 0; b < 10; ++b) {
        int bm1 = (b + 9) % 10;
        float v = (sm[b] - sm[bm1]) + nb[bm1];
        v += __shfl_xor(v, 1);
        v += __shfl_xor(v, 2);
        if (r2 == 0) op[(size_t)b * 4096] = v * (1.0f / 64.0f);
    }
}

extern "C" void kernel_launch(void* const* d_in, const int* in_sizes, int n_in,
                              void* d_out, int out_size, void* d_ws, size_t ws_size,
                              hipStream_t stream) {
    const float* x = (const float*)d_in[0];
    float* out = (float*)d_out;
    const int total = 16 * 64 * 64 * 4;  // 262144 threads, 16 px each
    hog_kernel<<<total / 256, 256, 0, stream>>>(x, out);
}

// Round 13
// 17.604 us; speedup vs baseline: 1.7479x; 1.7479x over previous
//
#include <hip/hip_runtime.h>
#include <math.h>

#define THR_BASE 9.42477e-5f  // sin(3e-4 * pi/10): proven margin (rounds 2-12)
#define KFOLD 256.0f          // count-fold constant: acc += mag + KFOLD
#define KFOLD_INV 0.00390625f // 1/256

// Predicated (border) halo row load
#define LOADROW_P(DST, RR)                                                \
    {                                                                     \
        int rr = (RR);                                                    \
        bool rok = (rr >= 0) && (rr < 512);                               \
        const float* rp = img + (size_t)(rok ? rr : row0) * 512;          \
        const float4* rp4 = (const float4*)(rp + col0);                   \
        float4 v0 = rp4[0], v1 = rp4[1];                                  \
        float lf = rp[(cw > 0) ? (col0 - 1) : col0];                      \
        float rt = rp[(cw < 63) ? (col0 + 8) : col0];                     \
        float m = rok ? 1.0f : 0.0f;                                      \
        DST[0] = (cw > 0 && rok) ? lf : 0.0f;                             \
        DST[1] = v0.x * m; DST[2] = v0.y * m;                             \
        DST[3] = v0.z * m; DST[4] = v0.w * m;                             \
        DST[5] = v1.x * m; DST[6] = v1.y * m;                             \
        DST[7] = v1.z * m; DST[8] = v1.w * m;                             \
        DST[9] = (cw < 63 && rok) ? rt : 0.0f;                            \
    }

// Unpredicated (interior-wave) halo row load
#define LOADROW_F(DST, RR)                                                \
    {                                                                     \
        const float* rp = img + (size_t)(RR) * 512;                       \
        const float4* rp4 = (const float4*)(rp + col0);                   \
        float4 v0 = rp4[0], v1 = rp4[1];                                  \
        DST[0] = rp[col0 - 1];                                            \
        DST[1] = v0.x; DST[2] = v0.y; DST[3] = v0.z; DST[4] = v0.w;       \
        DST[5] = v1.x; DST[6] = v1.y; DST[7] = v1.z; DST[8] = v1.w;       \
        DST[9] = rp[col0 + 8];                                            \
    }

// x: (16,1,512,512) f32 ; out: (16,10,64,64) f32
// thread t -> (n, ch, cw, r2): 4 threads/cell, 16 px/thread.
// Cumulative-threshold binning: monotone sector tests I_k = (m_k>=0) give
// fl = #ones (A side) / 9-#ones (B side); accumulate sign-masked magK into
// A_0..A_4 / B_0..B_4 (registers), telescope in the tail. No select-chain.
__global__ void __launch_bounds__(256) hog_kernel(const float* __restrict__ x,
                                                  float* __restrict__ out) {
    int t    = blockIdx.x * 256 + threadIdx.x;
    int r2   = t & 3;            // row-pair within cell
    int cell = t >> 2;           // 0 .. 65535
    int cw   = cell & 63;
    int ch   = (cell >> 6) & 63;
    int n    = cell >> 12;

    const float* img = x + (size_t)n * (512 * 512);
    int row0 = ch * 8 + r2 * 2;  // first of this thread's 2 pixel rows
    int col0 = cw * 8;

    // ---- Phase 1: 4 halo rows -> dd (col sums) / uu (row diffs) ----
    float dd0[10], dd1[10], uu0[10], uu1[10];
    {
        float t0[10], t1[10], t2[10], t3[10];
        bool border = (cw == 0) | (cw == 63)
                    | ((ch == 0) & (r2 == 0)) | ((ch == 63) & (r2 == 3));
        if (__any((int)border)) {
            LOADROW_P(t0, row0 - 1)
            LOADROW_P(t1, row0)
            LOADROW_P(t2, row0 + 1)
            LOADROW_P(t3, row0 + 2)
        } else {
            LOADROW_F(t0, row0 - 1)
            LOADROW_F(t1, row0)
            LOADROW_F(t2, row0 + 1)
            LOADROW_F(t3, row0 + 2)
        }
#pragma unroll
        for (int c = 0; c < 10; ++c) {
            dd0[c] = fmaf(2.0f, t1[c], t0[c] + t2[c]);  // pixel row row0
            dd1[c] = fmaf(2.0f, t2[c], t1[c] + t3[c]);  // pixel row row0+1
            uu0[c] = t0[c] - t2[c];
            uu1[c] = t1[c] - t3[c];
        }
    }   // t0..t3 dead here

    // ---- Phase 2: all 16 gx / gy ----
    float gx[16], gy[16];
#pragma unroll
    for (int c = 0; c < 8; ++c) {
        gx[c]     = dd0[c] - dd0[c + 2];
        gx[8 + c] = dd1[c] - dd1[c + 2];
        gy[c]     = fmaf(2.0f, uu0[c + 1], uu0[c] + uu0[c + 2]);
        gy[8 + c] = fmaf(2.0f, uu1[c + 1], uu1[c] + uu1[c + 2]);
    }

    // ---- Phase 3: hot loop over 16 pixels, cumulative accumulate ----
    float accA[5], accB[5];
#pragma unroll
    for (int j = 0; j < 5; ++j) { accA[j] = 0.0f; accB[j] = 0.0f; }
    unsigned bmask = 0u;            // boundary-pixel flags (rare), 16 bits

#pragma unroll
    for (int p = 0; p < 16; ++p) {
        float gxc = gx[p], gyc = gy[p];
        float mag = __builtin_amdgcn_sqrtf(fmaf(gxc, gxc, gyc * gyc));
        float a = fabsf(gxc), b = fabsf(gyc);

        // Sector tests: m_k = a*cos(k*pi/10) - b*sin(k*pi/10), k=1..4
        // (monotone decreasing in k for a,b >= 0)
        float m1 = fmaf(a, 0.95105651629515353f, -(b * 0.30901699437494740f));
        float m2 = fmaf(a, 0.80901699437494745f, -(b * 0.58778525229247314f));
        float m3 = fmaf(a, 0.58778525229247314f, -(b * 0.80901699437494745f));
        float m4 = fmaf(a, 0.30901699437494740f, -(b * 0.95105651629515353f));

        int k1 = __float_as_int(m1) >> 31;   // all-ones iff m1 < 0 (sign bit)
        int k2 = __float_as_int(m2) >> 31;
        int k3 = __float_as_int(m3) >> 31;
        int k4 = __float_as_int(m4) >> 31;
        int qm = (__float_as_int(gxc) ^ __float_as_int(gyc)) >> 31; // qq mask

        float magK = mag + KFOLD;
        float magA = __int_as_float(__float_as_int(magK) & ~qm);  // qq=0 side
        float magB = magK - magA;                                 // qq=1 side

        accA[0] += magA;
        accB[0] += magB;
        accA[1] += __int_as_float(__float_as_int(magA) & ~k1);
        accB[1] += __int_as_float(__float_as_int(magB) & ~k1);
        accA[2] += __int_as_float(__float_as_int(magA) & ~k2);
        accB[2] += __int_as_float(__float_as_int(magB) & ~k2);
        accA[3] += __int_as_float(__float_as_int(magA) & ~k3);
        accB[3] += __int_as_float(__float_as_int(magB) & ~k3);
        accA[4] += __int_as_float(__float_as_int(magA) & ~k4);
        accB[4] += __int_as_float(__float_as_int(magB) & ~k4);

        float dmin = fminf(fminf(fminf(fabsf(m1), fabsf(m2)),
                                 fminf(fabsf(m3), fabsf(m4))),
                           fminf(a, b));
        bmask = (dmin < THR_BASE * fmaxf(mag, 1.0f)) ? (bmask | (1u << p)) : bmask;
    }

    // ---- Rare fixup: undo fast contribution, apply exact f64 sector ----
    while (__any((int)(bmask != 0u))) {
        if (bmask) {
            int p = (int)__builtin_ctz(bmask);
            bmask &= bmask - 1u;
            int prow = row0 + (p >> 3);
            int pc   = col0 + (p & 7);
            int rm = prow - 1, rq = prow + 1;
            int cm = pc - 1, cp = pc + 1;
            bool rmok = rm >= 0, rqok = rq < 512;
            bool cmok = cm >= 0, cpok = cp < 512;
            float w00 = (rmok && cmok) ? img[(size_t)rm * 512 + cm] : 0.0f;
            float w01 = rmok ? img[(size_t)rm * 512 + pc] : 0.0f;
            float w02 = (rmok && cpok) ? img[(size_t)rm * 512 + cp] : 0.0f;
            float w10 = cmok ? img[(size_t)prow * 512 + cm] : 0.0f;
            float w12 = cpok ? img[(size_t)prow * 512 + cp] : 0.0f;
            float w20 = (rqok && cmok) ? img[(size_t)rq * 512 + cm] : 0.0f;
            float w21 = rqok ? img[(size_t)rq * 512 + pc] : 0.0f;
            float w22 = (rqok && cpok) ? img[(size_t)rq * 512 + cp] : 0.0f;

            // Bit-exact replication of the fast path (same op forms/values)
            float gxf = fmaf(2.0f, w10, w00 + w20) - fmaf(2.0f, w12, w02 + w22);
            float gyf = fmaf(2.0f, w01 - w21, (w00 - w20) + (w02 - w22));
            float magf = __builtin_amdgcn_sqrtf(fmaf(gxf, gxf, gyf * gyf));
            int negf = (int)(__float_as_uint(fmaf(fabsf(gxf), 0.95105651629515353f, -(fabsf(gyf) * 0.30901699437494740f))) >> 31)
                     + (int)(__float_as_uint(fmaf(fabsf(gxf), 0.80901699437494745f, -(fabsf(gyf) * 0.58778525229247314f))) >> 31)
                     + (int)(__float_as_uint(fmaf(fabsf(gxf), 0.58778525229247314f, -(fabsf(gyf) * 0.80901699437494745f))) >> 31)
                     + (int)(__float_as_uint(fmaf(fabsf(gxf), 0.30901699437494740f, -(fabsf(gyf) * 0.95105651629515353f))) >> 31);
            bool qqf = (((__float_as_uint(gxf) ^ __float_as_uint(gyf)) >> 31) != 0u);
            int onesf = 4 - negf;   // fast path added to side[qqf], j=0..onesf

            // Undo fast contribution (cumulative coordinates)
            float uv = -(magf + KFOLD);
#pragma unroll
            for (int j = 0; j < 5; ++j) {
                accA[j] += (!qqf && j <= onesf) ? uv : 0.0f;
                accB[j] += ( qqf && j <= onesf) ? uv : 0.0f;
            }

            // Exact f64 sector classification (no atan2).
            double gxd = (((((double)w00 - (double)w02) + 2.0 * (double)w10)
                           - 2.0 * (double)w12) + (double)w20) - (double)w22;
            double gyd = (((((double)w00 + 2.0 * (double)w01) + (double)w02)
                           - (double)w20) - 2.0 * (double)w21) - (double)w22;
            bool sideB;
            int onese;
            float mvals;
            if (gxd == 0.0) {        // p = 0 / +-10 -> bin 0 (A side, s=0)
                sideB = false; onese = 0; mvals = 1.0f;
            } else if (gyd == 0.0) { // p = +-5 -> bin 5 (B side, s=4)
                sideB = true; onese = 4; mvals = 1.0f;
            } else {
                double ad = fabs(gxd), bd = fabs(gyd);
                double M1 = fma(ad, 0.95105651629515353118, -(bd * 0.30901699437494742410));
                double M2 = fma(ad, 0.80901699437494742410, -(bd * 0.58778525229247312917));
                double M3 = fma(ad, 0.58778525229247312917, -(bd * 0.80901699437494742410));
                double M4 = fma(ad, 0.30901699437494742410, -(bd * 0.95105651629515353118));
                int negd = (int)(M1 < 0.0) + (int)(M2 < 0.0)
                         + (int)(M3 < 0.0) + (int)(M4 < 0.0);
                sideB = (gxd < 0.0) != (gyd < 0.0);
                onese = 4 - negd;
                mvals = magf;
            }
            float av = mvals + KFOLD;
#pragma unroll
            for (int j = 0; j < 5; ++j) {
                accA[j] += (!sideB && j <= onese) ? av : 0.0f;
                accB[j] += ( sideB && j <= onese) ? av : 0.0f;
            }
        }
    }

    // ---- Tail: unfold counts, telescope, combine, reduce, store ----
    float Am[5], An[5], Bm[5], Bn[5];
#pragma unroll
    for (int j = 0; j < 5; ++j) {
        float qa = rintf(accA[j] * KFOLD_INV);
        Am[j] = fmaf(qa, -KFOLD, accA[j]);
        An[j] = qa;
        float qb = rintf(accB[j] * KFOLD_INV);
        Bm[j] = fmaf(qb, -KFOLD, accB[j]);
        Bn[j] = qb;
    }
    // Per-bin mag sums M[b] and counts C[b]
    float M[10], C[10];
#pragma unroll
    for (int s = 0; s < 5; ++s) {
        float am1 = (s < 4) ? Am[s + 1] : 0.0f;
        float an1 = (s < 4) ? An[s + 1] : 0.0f;
        M[s] = Am[s] - am1;             // bin s (A side), s = #ones
        C[s] = An[s] - an1;
        float bm1 = (s < 4) ? Bm[s + 1] : 0.0f;
        float bn1 = (s < 4) ? Bn[s + 1] : 0.0f;
        M[9 - s] = Bm[s] - bm1;         // bin 9-s (B side)
        C[9 - s] = Bn[s] - bn1;
    }

    float* op = out + (((size_t)n * 10) * 64 + ch) * 64 + cw;
#pragma unroll
    for (int b = 0; b < 10; ++b) {
        int bm1 = (b + 9) % 10;
        float v = (M[b] - M[bm1]) + C[bm1];
        v += __shfl_xor(v, 1);
        v += __shfl_xor(v, 2);
        if (r2 == 0) op[(size_t)b * 4096] = v * (1.0f / 64.0f);
    }
}

extern "C" void kernel_launch(void* const* d_in, const int* in_sizes, int n_in,
                              void* d_out, int out_size, void* d_ws, size_t ws_size,
                              hipStream_t stream) {
    const float* x = (const float*)d_in[0];
    float* out = (float*)d_out;
    const int total = 16 * 64 * 64 * 4;  // 262144 threads, 16 px each
    hog_kernel<<<total / 256, 256, 0, stream>>>(x, out);
}

// Round 14
// 16.575 us; speedup vs baseline: 1.8564x; 1.0621x over previous
//
#include <hip/hip_runtime.h>
#include <math.h>

#define THR_BASE 9.42477e-5f  // sin(3e-4 * pi/10): proven margin (rounds 2-13)
#define KFOLD 256.0f          // count-fold constant: acc += mag + KFOLD
#define KFOLD_INV 0.00390625f // 1/256
#define LSTRIDE 532           // dwords/LDS row: 16B-aligned rows, no 2-row bank resonance

// x: (16,1,512,512) f32 ; out: (16,10,64,64) f32
// Block = one cell-row (ch, n uniform). Stage 10 image rows into zero-padded
// LDS (img col c at L = c+5; L=4/517 are the zero pads), then branch-free
// per-thread halo reads via ds_read_b128. Binning: cumulative-threshold in
// registers (r13-proven). 4 threads/cell, 16 px/thread.
__global__ void __launch_bounds__(256) hog_kernel(const float* __restrict__ x,
                                                  float* __restrict__ out) {
    __shared__ float s[10 * LSTRIDE];

    int tid = threadIdx.x;
    int blk = blockIdx.x;
    int ch  = blk & 63;          // block-uniform cell-row
    int n   = blk >> 6;          // block-uniform image
    const float* img = x + (size_t)n * (512 * 512);
    int R0 = ch * 8 - 1;         // first staged image row

    // ---- Stage: 10 rows x 512 cols (1280 float4, 5 per thread), coalesced.
#pragma unroll
    for (int k = 0; k < 5; ++k) {
        int j = tid + k * 256;           // 0..1279
        int lrow = j >> 7;               // 128 float4 per row
        int cb = j & 127;                // float4 index within row
        int R = R0 + lrow;
        bool rok = (R >= 0) && (R < 512);
        const float4* gp = (const float4*)(img + (size_t)(rok ? R : 0) * 512) + cb;
        float4 v = *gp;
        float m = rok ? 1.0f : 0.0f;     // zero out-of-range rows
        int L = lrow * LSTRIDE + 5 + cb * 4;
        s[L + 0] = v.x * m;
        s[L + 1] = v.y * m;
        s[L + 2] = v.z * m;
        s[L + 3] = v.w * m;
    }
    if (tid < 10) {                       // zero pads: img col -1 and 512
        s[tid * LSTRIDE + 4]   = 0.0f;
        s[tid * LSTRIDE + 517] = 0.0f;
    }
    __syncthreads();

    int r2   = tid & 3;          // row-pair within cell
    int cw   = tid >> 2;         // cell within the block's row (0..63)
    int row0 = ch * 8 + r2 * 2;  // first of this thread's 2 pixel rows
    int col0 = cw * 8;

    // ---- Halo read from LDS: 4 rows x 10 cols, branch-free, zero-padded.
    // Local row of image row (row0-1+d) is 2*r2+d; L(col0-1) = 8*cw+4.
    float t0[10], t1[10], t2[10], t3[10];
    {
        int base = (2 * r2) * LSTRIDE + 8 * cw + 4;
#define READROW(DST, D)                                                   \
        {                                                                 \
            const float* rp = &s[base + (D) * LSTRIDE];                   \
            float4 a4 = *(const float4*)(rp);                             \
            float4 b4 = *(const float4*)(rp + 4);                         \
            DST[0] = a4.x; DST[1] = a4.y; DST[2] = a4.z; DST[3] = a4.w;   \
            DST[4] = b4.x; DST[5] = b4.y; DST[6] = b4.z; DST[7] = b4.w;   \
            DST[8] = rp[8]; DST[9] = rp[9];                               \
        }
        READROW(t0, 0)
        READROW(t1, 1)
        READROW(t2, 2)
        READROW(t3, 3)
#undef READROW
    }

    // ---- dd (col sums) / uu (row diffs) per pixel row ----
    float dd0[10], dd1[10], uu0[10], uu1[10];
#pragma unroll
    for (int c = 0; c < 10; ++c) {
        dd0[c] = fmaf(2.0f, t1[c], t0[c] + t2[c]);  // pixel row row0
        dd1[c] = fmaf(2.0f, t2[c], t1[c] + t3[c]);  // pixel row row0+1
        uu0[c] = t0[c] - t2[c];
        uu1[c] = t1[c] - t3[c];
    }

    // ---- all 16 gx / gy ----
    float gx[16], gy[16];
#pragma unroll
    for (int c = 0; c < 8; ++c) {
        gx[c]     = dd0[c] - dd0[c + 2];
        gx[8 + c] = dd1[c] - dd1[c + 2];
        gy[c]     = fmaf(2.0f, uu0[c + 1], uu0[c] + uu0[c + 2]);
        gy[8 + c] = fmaf(2.0f, uu1[c + 1], uu1[c] + uu1[c + 2]);
    }

    // ---- hot loop: cumulative-threshold accumulate (r13-proven) ----
    float accA[5], accB[5];
#pragma unroll
    for (int j = 0; j < 5; ++j) { accA[j] = 0.0f; accB[j] = 0.0f; }
    unsigned bmask = 0u;            // boundary-pixel flags (rare), 16 bits

#pragma unroll
    for (int p = 0; p < 16; ++p) {
        float gxc = gx[p], gyc = gy[p];
        float mag = __builtin_amdgcn_sqrtf(fmaf(gxc, gxc, gyc * gyc));
        float a = fabsf(gxc), b = fabsf(gyc);

        // Sector tests: m_k = a*cos(k*pi/10) - b*sin(k*pi/10), k=1..4
        float m1 = fmaf(a, 0.95105651629515353f, -(b * 0.30901699437494740f));
        float m2 = fmaf(a, 0.80901699437494745f, -(b * 0.58778525229247314f));
        float m3 = fmaf(a, 0.58778525229247314f, -(b * 0.80901699437494745f));
        float m4 = fmaf(a, 0.30901699437494740f, -(b * 0.95105651629515353f));

        int k1 = __float_as_int(m1) >> 31;   // all-ones iff m_k < 0
        int k2 = __float_as_int(m2) >> 31;
        int k3 = __float_as_int(m3) >> 31;
        int k4 = __float_as_int(m4) >> 31;
        int qm = (__float_as_int(gxc) ^ __float_as_int(gyc)) >> 31; // qq mask

        float magK = mag + KFOLD;
        float magA = __int_as_float(__float_as_int(magK) & ~qm);  // qq=0 side
        float magB = magK - magA;                                 // qq=1 side

        accA[0] += magA;
        accB[0] += magB;
        accA[1] += __int_as_float(__float_as_int(magA) & ~k1);
        accB[1] += __int_as_float(__float_as_int(magB) & ~k1);
        accA[2] += __int_as_float(__float_as_int(magA) & ~k2);
        accB[2] += __int_as_float(__float_as_int(magB) & ~k2);
        accA[3] += __int_as_float(__float_as_int(magA) & ~k3);
        accB[3] += __int_as_float(__float_as_int(magB) & ~k3);
        accA[4] += __int_as_float(__float_as_int(magA) & ~k4);
        accB[4] += __int_as_float(__float_as_int(magB) & ~k4);

        // min3-friendly nesting: min(min(min(|m1|,|m2|),|m3|), min(min(|m4|,a),b))
        float dmin = fminf(fminf(fminf(fabsf(m1), fabsf(m2)), fabsf(m3)),
                           fminf(fminf(fabsf(m4), a), b));
        bmask = (dmin < THR_BASE * fmaxf(mag, 1.0f)) ? (bmask | (1u << p)) : bmask;
    }

    // ---- Rare fixup: undo fast contribution, apply exact f64 sector ----
    while (__any((int)(bmask != 0u))) {
        if (bmask) {
            int p = (int)__builtin_ctz(bmask);
            bmask &= bmask - 1u;
            int prow = row0 + (p >> 3);
            int pc   = col0 + (p & 7);
            int rm = prow - 1, rq = prow + 1;
            int cm = pc - 1, cp = pc + 1;
            bool rmok = rm >= 0, rqok = rq < 512;
            bool cmok = cm >= 0, cpok = cp < 512;
            float w00 = (rmok && cmok) ? img[(size_t)rm * 512 + cm] : 0.0f;
            float w01 = rmok ? img[(size_t)rm * 512 + pc] : 0.0f;
            float w02 = (rmok && cpok) ? img[(size_t)rm * 512 + cp] : 0.0f;
            float w10 = cmok ? img[(size_t)prow * 512 + cm] : 0.0f;
            float w12 = cpok ? img[(size_t)prow * 512 + cp] : 0.0f;
            float w20 = (rqok && cmok) ? img[(size_t)rq * 512 + cm] : 0.0f;
            float w21 = rqok ? img[(size_t)rq * 512 + pc] : 0.0f;
            float w22 = (rqok && cpok) ? img[(size_t)rq * 512 + cp] : 0.0f;

            // Bit-exact replication of the fast path (same op forms/values)
            float gxf = fmaf(2.0f, w10, w00 + w20) - fmaf(2.0f, w12, w02 + w22);
            float gyf = fmaf(2.0f, w01 - w21, (w00 - w20) + (w02 - w22));
            float magf = __builtin_amdgcn_sqrtf(fmaf(gxf, gxf, gyf * gyf));
            int negf = (int)(__float_as_uint(fmaf(fabsf(gxf), 0.95105651629515353f, -(fabsf(gyf) * 0.30901699437494740f))) >> 31)
                     + (int)(__float_as_uint(fmaf(fabsf(gxf), 0.80901699437494745f, -(fabsf(gyf) * 0.58778525229247314f))) >> 31)
                     + (int)(__float_as_uint(fmaf(fabsf(gxf), 0.58778525229247314f, -(fabsf(gyf) * 0.80901699437494745f))) >> 31)
                     + (int)(__float_as_uint(fmaf(fabsf(gxf), 0.30901699437494740f, -(fabsf(gyf) * 0.95105651629515353f))) >> 31);
            bool qqf = (((__float_as_uint(gxf) ^ __float_as_uint(gyf)) >> 31) != 0u);
            int onesf = 4 - negf;   // fast path added to side[qqf], j=0..onesf

            // Undo fast contribution (cumulative coordinates)
            float uv = -(magf + KFOLD);
#pragma unroll
            for (int j = 0; j < 5; ++j) {
                accA[j] += (!qqf && j <= onesf) ? uv : 0.0f;
                accB[j] += ( qqf && j <= onesf) ? uv : 0.0f;
            }

            // Exact f64 sector classification (no atan2).
            double gxd = (((((double)w00 - (double)w02) + 2.0 * (double)w10)
                           - 2.0 * (double)w12) + (double)w20) - (double)w22;
            double gyd = (((((double)w00 + 2.0 * (double)w01) + (double)w02)
                           - (double)w20) - 2.0 * (double)w21) - (double)w22;
            bool sideB;
            int onese;
            float mvals;
            if (gxd == 0.0) {        // p = 0 / +-10 -> bin 0 (A side, s=0)
                sideB = false; onese = 0; mvals = 1.0f;
            } else if (gyd == 0.0) { // p = +-5 -> bin 5 (B side, s=4)
                sideB = true; onese = 4; mvals = 1.0f;
            } else {
                double ad = fabs(gxd), bd = fabs(gyd);
                double M1 = fma(ad, 0.95105651629515353118, -(bd * 0.30901699437494742410));
                double M2 = fma(ad, 0.80901699437494742410, -(bd * 0.58778525229247312917));
                double M3 = fma(ad, 0.58778525229247312917, -(bd * 0.80901699437494742410));
                double M4 = fma(ad, 0.30901699437494742410, -(bd * 0.95105651629515353118));
                int negd = (int)(M1 < 0.0) + (int)(M2 < 0.0)
                         + (int)(M3 < 0.0) + (int)(M4 < 0.0);
                sideB = (gxd < 0.0) != (gyd < 0.0);
                onese = 4 - negd;
                mvals = magf;
            }
            float av = mvals + KFOLD;
#pragma unroll
            for (int j = 0; j < 5; ++j) {
                accA[j] += (!sideB && j <= onese) ? av : 0.0f;
                accB[j] += ( sideB && j <= onese) ? av : 0.0f;
            }
        }
    }

    // ---- Tail: unfold counts, telescope, combine, reduce, store ----
    float Am[5], An[5], Bm[5], Bn[5];
#pragma unroll
    for (int j = 0; j < 5; ++j) {
        float qa = rintf(accA[j] * KFOLD_INV);
        Am[j] = fmaf(qa, -KFOLD, accA[j]);
        An[j] = qa;
        float qb = rintf(accB[j] * KFOLD_INV);
        Bm[j] = fmaf(qb, -KFOLD, accB[j]);
        Bn[j] = qb;
    }
    float M[10], C[10];
#pragma unroll
    for (int sdx = 0; sdx < 5; ++sdx) {
        float am1 = (sdx < 4) ? Am[sdx + 1] : 0.0f;
        float an1 = (sdx < 4) ? An[sdx + 1] : 0.0f;
        M[sdx] = Am[sdx] - am1;             // bin s (A side), s = #ones
        C[sdx] = An[sdx] - an1;
        float bm1 = (sdx < 4) ? Bm[sdx + 1] : 0.0f;
        float bn1 = (sdx < 4) ? Bn[sdx + 1] : 0.0f;
        M[9 - sdx] = Bm[sdx] - bm1;         // bin 9-s (B side)
        C[9 - sdx] = Bn[sdx] - bn1;
    }

    float* op = out + (((size_t)n * 10) * 64 + ch) * 64 + cw;
#pragma unroll
    for (int b = 0; b < 10; ++b) {
        int bm1 = (b + 9) % 10;
        float v = (M[b] - M[bm1]) + C[bm1];
        v += __shfl_xor(v, 1);
        v += __shfl_xor(v, 2);
        if (r2 == 0) op[(size_t)b * 4096] = v * (1.0f / 64.0f);
    }
}

extern "C" void kernel_launch(void* const* d_in, const int* in_sizes, int n_in,
                              void* d_out, int out_size, void* d_ws, size_t ws_size,
                              hipStream_t stream) {
    const float* x = (const float*)d_in[0];
    float* out = (float*)d_out;
    const int total = 16 * 64 * 64 * 4;  // 262144 threads, 16 px each
    hog_kernel<<<total / 256, 256, 0, stream>>>(x, out);
}

// Round 15
// 15.232 us; speedup vs baseline: 2.0201x; 1.0882x over previous
//
#include <hip/hip_runtime.h>
#include <math.h>

// sin(3e-5 * pi/10): 10x tighter than rounds 2-14 (was 3e-4). Error budget:
// atan2f <= 2ulp ~ 7.6e-7 p-units; conv cancellation amplification ~1.5e-6.
// Band distance 9.42e-6 is ~20x both -> our fp32 path and the np reference
// agree on every pixel outside the band; band pixels go to exact f64.
#define THR_BASE 9.42477e-6f
#define KFOLD 256.0f          // count-fold constant: acc += mag + KFOLD
#define KFOLD_INV 0.00390625f // 1/256
#define LSTRIDE 532           // dwords/LDS row (16B-aligned rows; 2x bank cost is the floor for this shape)

typedef float v2f __attribute__((ext_vector_type(2)));

// x: (16,1,512,512) f32 ; out: (16,10,64,64) f32
// Block = one cell-row (ch, n uniform). Stage 10 zero-padded rows in LDS;
// branch-free halo reads; cumulative-threshold binning with PACKED (A,B)
// accumulators (v_pk_add_f32). 4 threads/cell, 16 px/thread.
__global__ void __launch_bounds__(256) hog_kernel(const float* __restrict__ x,
                                                  float* __restrict__ out) {
    __shared__ float s[10 * LSTRIDE];

    int tid = threadIdx.x;
    int blk = blockIdx.x;
    int ch  = blk & 63;          // block-uniform cell-row
    int n   = blk >> 6;          // block-uniform image
    const float* img = x + (size_t)n * (512 * 512);
    int R0 = ch * 8 - 1;         // first staged image row

    // ---- Stage: 10 rows x 512 cols (1280 float4, 5 per thread), coalesced.
#pragma unroll
    for (int k = 0; k < 5; ++k) {
        int j = tid + k * 256;           // 0..1279
        int lrow = j >> 7;               // 128 float4 per row
        int cb = j & 127;                // float4 index within row
        int R = R0 + lrow;
        bool rok = (R >= 0) && (R < 512);
        const float4* gp = (const float4*)(img + (size_t)(rok ? R : 0) * 512) + cb;
        float4 v = *gp;
        float m = rok ? 1.0f : 0.0f;     // zero out-of-range rows
        int L = lrow * LSTRIDE + 5 + cb * 4;
        s[L + 0] = v.x * m;
        s[L + 1] = v.y * m;
        s[L + 2] = v.z * m;
        s[L + 3] = v.w * m;
    }
    if (tid < 10) {                       // zero pads: img col -1 and 512
        s[tid * LSTRIDE + 4]   = 0.0f;
        s[tid * LSTRIDE + 517] = 0.0f;
    }
    __syncthreads();

    int r2   = tid & 3;          // row-pair within cell
    int cw   = tid >> 2;         // cell within the block's row (0..63)
    int row0 = ch * 8 + r2 * 2;  // first of this thread's 2 pixel rows
    int col0 = cw * 8;

    // ---- Halo read from LDS: 4 rows x 10 cols, branch-free, zero-padded.
    float t0[10], t1[10], t2[10], t3[10];
    {
        int base = (2 * r2) * LSTRIDE + 8 * cw + 4;
#define READROW(DST, D)                                                   \
        {                                                                 \
            const float* rp = &s[base + (D) * LSTRIDE];                   \
            float4 a4 = *(const float4*)(rp);                             \
            float4 b4 = *(const float4*)(rp + 4);                         \
            DST[0] = a4.x; DST[1] = a4.y; DST[2] = a4.z; DST[3] = a4.w;   \
            DST[4] = b4.x; DST[5] = b4.y; DST[6] = b4.z; DST[7] = b4.w;   \
            DST[8] = rp[8]; DST[9] = rp[9];                               \
        }
        READROW(t0, 0)
        READROW(t1, 1)
        READROW(t2, 2)
        READROW(t3, 3)
#undef READROW
    }

    // ---- dd (col sums) / uu (row diffs) per pixel row ----
    float dd0[10], dd1[10], uu0[10], uu1[10];
#pragma unroll
    for (int c = 0; c < 10; ++c) {
        dd0[c] = fmaf(2.0f, t1[c], t0[c] + t2[c]);  // pixel row row0
        dd1[c] = fmaf(2.0f, t2[c], t1[c] + t3[c]);  // pixel row row0+1
        uu0[c] = t0[c] - t2[c];
        uu1[c] = t1[c] - t3[c];
    }

    // ---- all 16 gx / gy ----
    float gx[16], gy[16];
#pragma unroll
    for (int c = 0; c < 8; ++c) {
        gx[c]     = dd0[c] - dd0[c + 2];
        gx[8 + c] = dd1[c] - dd1[c + 2];
        gy[c]     = fmaf(2.0f, uu0[c + 1], uu0[c] + uu0[c + 2]);
        gy[8 + c] = fmaf(2.0f, uu1[c + 1], uu1[c] + uu1[c + 2]);
    }

    // ---- hot loop: packed cumulative-threshold accumulate ----
    v2f acc[5];                     // .x = A side (qq=0), .y = B side (qq=1)
#pragma unroll
    for (int j = 0; j < 5; ++j) acc[j] = (v2f)(0.0f);
    unsigned bmask = 0u;            // boundary-pixel flags (rare), 16 bits

#pragma unroll
    for (int p = 0; p < 16; ++p) {
        float gxc = gx[p], gyc = gy[p];
        float mag = __builtin_amdgcn_sqrtf(fmaf(gxc, gxc, gyc * gyc));
        float a = fabsf(gxc), b = fabsf(gyc);

        // Sector tests: m_k = a*cos(k*pi/10) - b*sin(k*pi/10), k=1..4
        float m1 = fmaf(a, 0.95105651629515353f, -(b * 0.30901699437494740f));
        float m2 = fmaf(a, 0.80901699437494745f, -(b * 0.58778525229247314f));
        float m3 = fmaf(a, 0.58778525229247314f, -(b * 0.80901699437494745f));
        float m4 = fmaf(a, 0.30901699437494740f, -(b * 0.95105651629515353f));

        int k1 = __float_as_int(m1) >> 31;   // all-ones iff m_k < 0
        int k2 = __float_as_int(m2) >> 31;
        int k3 = __float_as_int(m3) >> 31;
        int k4 = __float_as_int(m4) >> 31;
        int qm = (__float_as_int(gxc) ^ __float_as_int(gyc)) >> 31; // qq mask

        int fK = __float_as_int(mag + KFOLD);
        int fA = fK & ~qm;                   // magK on A side, else 0
        int fB = fK & qm;                    // magK on B side, else 0

        v2f v0; v0.x = __int_as_float(fA);      v0.y = __int_as_float(fB);
        v2f v1; v1.x = __int_as_float(fA & ~k1); v1.y = __int_as_float(fB & ~k1);
        v2f v2; v2.x = __int_as_float(fA & ~k2); v2.y = __int_as_float(fB & ~k2);
        v2f v3; v3.x = __int_as_float(fA & ~k3); v3.y = __int_as_float(fB & ~k3);
        v2f v4; v4.x = __int_as_float(fA & ~k4); v4.y = __int_as_float(fB & ~k4);
        acc[0] += v0; acc[1] += v1; acc[2] += v2; acc[3] += v3; acc[4] += v4;

        float dmin = fminf(fminf(fminf(fabsf(m1), fabsf(m2)), fabsf(m3)),
                           fminf(fminf(fabsf(m4), a), b));
        bmask = (dmin < THR_BASE * fmaxf(mag, 1.0f)) ? (bmask | (1u << p)) : bmask;
    }

    // ---- Rare fixup: undo fast contribution, apply exact f64 sector ----
    while (__any((int)(bmask != 0u))) {
        if (bmask) {
            int p = (int)__builtin_ctz(bmask);
            bmask &= bmask - 1u;
            int prow = row0 + (p >> 3);
            int pc   = col0 + (p & 7);
            int rm = prow - 1, rq = prow + 1;
            int cm = pc - 1, cp = pc + 1;
            bool rmok = rm >= 0, rqok = rq < 512;
            bool cmok = cm >= 0, cpok = cp < 512;
            float w00 = (rmok && cmok) ? img[(size_t)rm * 512 + cm] : 0.0f;
            float w01 = rmok ? img[(size_t)rm * 512 + pc] : 0.0f;
            float w02 = (rmok && cpok) ? img[(size_t)rm * 512 + cp] : 0.0f;
            float w10 = cmok ? img[(size_t)prow * 512 + cm] : 0.0f;
            float w12 = cpok ? img[(size_t)prow * 512 + cp] : 0.0f;
            float w20 = (rqok && cmok) ? img[(size_t)rq * 512 + cm] : 0.0f;
            float w21 = rqok ? img[(size_t)rq * 512 + pc] : 0.0f;
            float w22 = (rqok && cpok) ? img[(size_t)rq * 512 + cp] : 0.0f;

            // Bit-exact replication of the fast path (same op forms/values)
            float gxf = fmaf(2.0f, w10, w00 + w20) - fmaf(2.0f, w12, w02 + w22);
            float gyf = fmaf(2.0f, w01 - w21, (w00 - w20) + (w02 - w22));
            float magf = __builtin_amdgcn_sqrtf(fmaf(gxf, gxf, gyf * gyf));
            int negf = (int)(__float_as_uint(fmaf(fabsf(gxf), 0.95105651629515353f, -(fabsf(gyf) * 0.30901699437494740f))) >> 31)
                     + (int)(__float_as_uint(fmaf(fabsf(gxf), 0.80901699437494745f, -(fabsf(gyf) * 0.58778525229247314f))) >> 31)
                     + (int)(__float_as_uint(fmaf(fabsf(gxf), 0.58778525229247314f, -(fabsf(gyf) * 0.80901699437494745f))) >> 31)
                     + (int)(__float_as_uint(fmaf(fabsf(gxf), 0.30901699437494740f, -(fabsf(gyf) * 0.95105651629515353f))) >> 31);
            bool qqf = (((__float_as_uint(gxf) ^ __float_as_uint(gyf)) >> 31) != 0u);
            int onesf = 4 - negf;   // fast path added to side[qqf], j=0..onesf

            // Undo fast contribution (cumulative coordinates)
            float uv = -(magf + KFOLD);
#pragma unroll
            for (int j = 0; j < 5; ++j) {
                acc[j].x += (!qqf && j <= onesf) ? uv : 0.0f;
                acc[j].y += ( qqf && j <= onesf) ? uv : 0.0f;
            }

            // Exact f64 sector classification (no atan2).
            double gxd = (((((double)w00 - (double)w02) + 2.0 * (double)w10)
                           - 2.0 * (double)w12) + (double)w20) - (double)w22;
            double gyd = (((((double)w00 + 2.0 * (double)w01) + (double)w02)
                           - (double)w20) - 2.0 * (double)w21) - (double)w22;
            bool sideB;
            int onese;
            float mvals;
            if (gxd == 0.0) {        // p = 0 / +-10 -> bin 0 (A side, s=0)
                sideB = false; onese = 0; mvals = 1.0f;
            } else if (gyd == 0.0) { // p = +-5 -> bin 5 (B side, s=4)
                sideB = true; onese = 4; mvals = 1.0f;
            } else {
                double ad = fabs(gxd), bd = fabs(gyd);
                double M1 = fma(ad, 0.95105651629515353118, -(bd * 0.30901699437494742410));
                double M2 = fma(ad, 0.80901699437494742410, -(bd * 0.58778525229247312917));
                double M3 = fma(ad, 0.58778525229247312917, -(bd * 0.80901699437494742410));
                double M4 = fma(ad, 0.30901699437494742410, -(bd * 0.95105651629515353118));
                int negd = (int)(M1 < 0.0) + (int)(M2 < 0.0)
                         + (int)(M3 < 0.0) + (int)(M4 < 0.0);
                sideB = (gxd < 0.0) != (gyd < 0.0);
                onese = 4 - negd;
                mvals = magf;
            }
            float av = mvals + KFOLD;
#pragma unroll
            for (int j = 0; j < 5; ++j) {
                acc[j].x += (!sideB && j <= onese) ? av : 0.0f;
                acc[j].y += ( sideB && j <= onese) ? av : 0.0f;
            }
        }
    }

    // ---- Tail: unfold counts, telescope, combine, reduce, store ----
    float Am[5], An[5], Bm[5], Bn[5];
#pragma unroll
    for (int j = 0; j < 5; ++j) {
        float qa = rintf(acc[j].x * KFOLD_INV);
        Am[j] = fmaf(qa, -KFOLD, acc[j].x);
        An[j] = qa;
        float qb = rintf(acc[j].y * KFOLD_INV);
        Bm[j] = fmaf(qb, -KFOLD, acc[j].y);
        Bn[j] = qb;
    }
    float M[10], C[10];
#pragma unroll
    for (int sdx = 0; sdx < 5; ++sdx) {
        float am1 = (sdx < 4) ? Am[sdx + 1] : 0.0f;
        float an1 = (sdx < 4) ? An[sdx + 1] : 0.0f;
        M[sdx] = Am[sdx] - am1;             // bin s (A side), s = #ones
        C[sdx] = An[sdx] - an1;
        float bm1 = (sdx < 4) ? Bm[sdx + 1] : 0.0f;
        float bn1 = (sdx < 4) ? Bn[sdx + 1] : 0.0f;
        M[9 - sdx] = Bm[sdx] - bm1;         // bin 9-s (B side)
        C[9 - sdx] = Bn[sdx] - bn1;
    }

    float* op = out + (((size_t)n * 10) * 64 + ch) * 64 + cw;
#pragma unroll
    for (int b = 0; b < 10; ++b) {
        int bm1 = (b + 9) % 10;
        float v = (M[b] - M[bm1]) + C[bm1];
        v += __shfl_xor(v, 1);
        v += __shfl_xor(v, 2);
        if (r2 == 0) op[(size_t)b * 4096] = v * (1.0f / 64.0f);
    }
}

extern "C" void kernel_launch(void* const* d_in, const int* in_sizes, int n_in,
                              void* d_out, int out_size, void* d_ws, size_t ws_size,
                              hipStream_t stream) {
    const float* x = (const float*)d_in[0];
    float* out = (float*)d_out;
    const int total = 16 * 64 * 64 * 4;  // 262144 threads, 16 px each
    hog_kernel<<<total / 256, 256, 0, stream>>>(x, out);
}